// Round 6
// baseline (400.348 us; speedup 1.0000x reference)
//
#include <hip/hip_runtime.h>

#define N_NODES   100000
#define N_EDGES   800000
#define NODE_DIM  64
#define EDGE_DIM  64
#define GEO_DIM   8
#define GEO_OUT   32
#define COND_DIM  512
#define N_GRAPHS  64

#define PREP_BLOCKS   65
#define NPROJ_BLOCKS  3125
#define EDGE_BLOCKS   3125   // 12500 waves x 4 tiles = 50000 = N_EDGES/16 exactly

typedef float          f32x4 __attribute__((ext_vector_type(4)));
typedef unsigned       u32x4 __attribute__((ext_vector_type(4)));
typedef unsigned short u16x8 __attribute__((ext_vector_type(8)));
typedef _Float16       f16x8 __attribute__((ext_vector_type(8)));
typedef _Float16       f16x2 __attribute__((ext_vector_type(2)));

__device__ __forceinline__ unsigned short f2h(float f) {   // f32 -> fp16 RNE
    _Float16 h = (_Float16)f;
    union { _Float16 h; unsigned short u; } cv;
    cv.h = h;
    return cv.u;
}
__device__ __forceinline__ f16x2 cvt2h(float lo, float hi) {
    f16x2 r;
    r[0] = (_Float16)lo;
    r[1] = (_Float16)hi;
    return r;
}

// ---------------------------------------------------------------------------
// pre: fused prep + nproj.
//   blocks 0..63   : FiLM gamma/beta2 per graph -> gbpack (fp16 pair per
//                    feature), XOR-swizzled: dword addr for (g, j) is
//                    g*64 + (((j>>2) ^ (g&15))<<2) + (j&3)  -- so edge-side
//                    random-graph ds_read_b128 spreads across LDS banks.
//   block  64      : Bfrag (fp16, 6144) in MFMA-fragment order:
//                    idx = ((c*4+t)*64 + lane)*8 + j holds
//                    B[k=c*32+(lane>>4)*8+j][n=t*16+(lane&15)] of folded 96x64:
//                    rows 0..63 = Wx[0:64]; 64..71 = Wg@Wx[64:96]; 72..95 = 0
//   blocks 65..    : nproj  n_projh[n][j] = fp16(node_feats[n] @ Wn[:,j] + bn[j])
// ---------------------------------------------------------------------------
__global__ __launch_bounds__(256) void pre_kernel(
        const float* __restrict__ cond, const float* __restrict__ Wc,
        const float* __restrict__ bc,   const float* __restrict__ Wg,
        const float* __restrict__ bg,   const float* __restrict__ Wx,
        const float* __restrict__ nf,   const float* __restrict__ Wn,
        const float* __restrict__ bn,
        unsigned* __restrict__ gbpack, unsigned short* __restrict__ Bfrag,
        unsigned short* __restrict__ nprojh) {
    int t = threadIdx.x;
    int g = blockIdx.x;
    if (g < N_GRAPHS) {
        __shared__ float condl[COND_DIM];
        __shared__ float gbl[128];
        for (int i = t; i < COND_DIM; i += 256) condl[i] = cond[g * COND_DIM + i];
        __syncthreads();
        if (t < 128) {
            float acc = bc[t];
            #pragma unroll 8
            for (int k = 0; k < COND_DIM; ++k) acc += condl[k] * Wc[k * 128 + t];
            gbl[t] = acc;
        }
        __syncthreads();
        if (t < 64) {
            float gam = gbl[t] + 1.0f;
            float bet = gbl[64 + t];
            float cv = 0.0f;
            #pragma unroll
            for (int i = 0; i < GEO_OUT; ++i) cv += bg[i] * Wx[(64 + i) * 64 + t];
            union { unsigned u; _Float16 h[2]; } pk;
            pk.h[0] = (_Float16)gam;
            pk.h[1] = (_Float16)(bet + cv * gam);
            gbpack[g * 64 + (((t >> 2) ^ (g & 15)) << 2) + (t & 3)] = pk.u;
        }
    } else if (g == N_GRAPHS) {
        for (int idx = t; idx < 6144; idx += 256) {
            int j    = idx & 7;
            int lane = (idx >> 3) & 63;
            int ct   = idx >> 9;
            int c    = ct >> 2, tt = ct & 3;
            int k = c * 32 + ((lane >> 4) & 3) * 8 + j;
            int n = tt * 16 + (lane & 15);
            float val;
            if (k < 64) {
                val = Wx[k * 64 + n];
            } else if (k < 72) {
                float s = 0.f;
                #pragma unroll
                for (int i = 0; i < GEO_OUT; ++i)
                    s += Wg[(k - 64) * GEO_OUT + i] * Wx[(64 + i) * 64 + n];
                val = s;
            } else {
                val = 0.f;
            }
            Bfrag[idx] = f2h(val);
        }
    } else {
        int lane = t & 63;
        int wid    = ((g - PREP_BLOCKS) * 256 + t) >> 6;
        const int nwaves = (NPROJ_BLOCKS * 256) >> 6;   // 12500
        float wcol[64];
        #pragma unroll
        for (int k = 0; k < 64; ++k) wcol[k] = Wn[k * 64 + lane];
        float bnl = bn[lane];
        for (int node = wid; node < N_NODES; node += nwaves) {
            int nu = __builtin_amdgcn_readfirstlane(node);
            const float* row = nf + (size_t)nu * 64;
            float a0 = 0.f, a1 = 0.f, a2 = 0.f, a3 = bnl;
            #pragma unroll
            for (int k = 0; k < 64; k += 4) {
                a0 = fmaf(row[k    ], wcol[k    ], a0);
                a1 = fmaf(row[k + 1], wcol[k + 1], a1);
                a2 = fmaf(row[k + 2], wcol[k + 2], a2);
                a3 = fmaf(row[k + 3], wcol[k + 3], a3);
            }
            nprojh[(size_t)nu * 64 + lane] = f2h((a0 + a1) + (a2 + a3));
        }
    }
}

// ---------------------------------------------------------------------------
// edge: per wave EXACTLY 4 tiles of 16 edges (grid must be EDGE_BLOCKS).
//   SWAPPED-OPERAND fp16 MFMA.  B fragments in REGISTERS (48 VGPR, loaded
//   once per wave from L2) -- R5 re-read them from LDS 12x per tile, making
//   the per-CU LDS pipe the bottleneck (24 b128 LDS ops/tile ~ 288 cyc).
//   Now 12 LDS ops/tile.  Dropping Bl also cuts LDS to 32KB/block ->
//   occupancy 12 -> 16 waves/CU.  Packed fp16 gamma/beta stay in LDS
//   (epilogue has zero global loads -> depth-2 gather prefetch never drained).
//   Transpose via rotate-swizzled LDS tile, contiguous 1KB nt wave stores.
// ---------------------------------------------------------------------------
__global__ __launch_bounds__(256, 4) void edge_kernel(
        const unsigned short* __restrict__ nprojh,
        const int*   __restrict__ eidx,
        const float* __restrict__ egeo,
        const int*   __restrict__ ebatch,
        const unsigned short* __restrict__ Bfrag,
        const unsigned* __restrict__ gbpack,
        float* __restrict__ out) {
    int lane = threadIdx.x & 63;
    int q  = lane >> 4;
    int mm = lane & 15;
    int wv = threadIdx.x >> 6;

    __shared__ unsigned GBl[4096];          // 16KB packed gamma/beta (swizzled)
    __shared__ float ldsT[4][16 * 64];      // 4KB per-wave transpose tile
    float* tileb = ldsT[wv];

    for (int i = threadIdx.x; i < 4096; i += 256)
        GBl[i] = gbpack[i];                 // already swizzled in global

    // B fragments -> registers (fragment-major, 12 x dwordx4 from L2)
    f16x8 bfr[3][4];
    #pragma unroll
    for (int c = 0; c < 3; ++c)
        #pragma unroll
        for (int t = 0; t < 4; ++t)
            bfr[c][t] = *(const f16x8*)(Bfrag + (size_t)((c * 4 + t) * 64 + lane) * 8);
    __syncthreads();

    // Rotate-swizzled transpose addresses (lane-only):
    // write (per t): float addr = mm*64 + ((t+mm)&3)*16 + q*4   (b128)
    // read  (per c): float addr = rbase + c*256                 (b128)
    const int wbase = mm * 64 + q * 4;
    const int rbase = (lane >> 4) * 64 +
                      (((((lane >> 2) & 3) + (lane >> 4)) & 3) << 4) +
                      (lane & 3) * 4;

    int wid = (blockIdx.x * blockDim.x + threadIdx.x) >> 6;
    const int nwaves = (EDGE_BLOCKS * 256) >> 6;        // 12500
    const int t0 = wid;                                  // tiles t0 + k*nwaves

    union HU { u16x8 v; f16x2 h[4]; unsigned u[4]; f16x8 f; };

    // persistent pipeline state: 2 gather sets + 2 pending index sets
    HU   sA0, sA1, dA0, dA1;  f32x4 gA0 = {0,0,0,0}, gA1 = {0,0,0,0};
    HU   sB0, sB1, dB0, dB1;  f32x4 gB0 = {0,0,0,0}, gB1 = {0,0,0,0};
    int  bqA[4], bqB[4];      // batch ids for epilogue rows of current tiles
    int  siA, diA, bqiA[4];   // indices for tile t0+2*nw (body A's prefetch)
    int  siB, diB, bqiB[4];   // indices for tile t0+3*nw (body B's prefetch)

#define LOAD_IDX(sI, dI, bqI, tl)                                              \
    {                                                                          \
        int e0n = (tl) * 16;                                                   \
        sI = __builtin_nontemporal_load(eidx + e0n + mm);                      \
        dI = __builtin_nontemporal_load(eidx + N_EDGES + e0n + mm);            \
        _Pragma("unroll")                                                      \
        for (int c = 0; c < 4; ++c)                                            \
            bqI[c] = __builtin_nontemporal_load(ebatch + e0n + c * 4 + q);     \
    }

#define GATHER(S0, S1, D0, D1, G0, G1, sI, dI, tl)                             \
    {                                                                          \
        const u16x8* ps = (const u16x8*)(nprojh + (size_t)(sI) * 64 + q * 8);  \
        const u16x8* pd = (const u16x8*)(nprojh + (size_t)(dI) * 64 + q * 8);  \
        S0.v = ps[0]; S1.v = ps[4];                                            \
        D0.v = pd[0]; D1.v = pd[4];                                            \
        if (q == 0) {                                                          \
            int e0n = (tl) * 16;                                               \
            G0 = __builtin_nontemporal_load((const f32x4*)(egeo + (size_t)(e0n + mm) * 8));     \
            G1 = __builtin_nontemporal_load((const f32x4*)(egeo + (size_t)(e0n + mm) * 8 + 4)); \
        }                                                                      \
    }

    // prologue: ALL index loads issue first (one latency, not two serial),
    // then the two gather sets for tiles t0, t0+nw.
    {
        int si0, di0, si1, di1;
        LOAD_IDX(si0, di0, bqA, t0);
        LOAD_IDX(si1, di1, bqB, t0 + nwaves);
        LOAD_IDX(siA, diA, bqiA, t0 + 2 * nwaves);
        LOAD_IDX(siB, diB, bqiB, t0 + 3 * nwaves);
        GATHER(sA0, sA1, dA0, dA1, gA0, gA1, si0, di0, t0);
        GATHER(sB0, sB1, dB0, dB1, gB0, gB1, si1, di1, t0 + nwaves);
    }

#define BODY(S0, S1, D0, D1, G0, G1, BQ, tl, PREF, sI, dI, bqI)                \
    {                                                                          \
        int e0 = (tl) * 16;                                                    \
        HU A0, A1, A2;                                                         \
        _Pragma("unroll")                                                      \
        for (int j = 0; j < 4; ++j) {                                          \
            A0.h[j] = S0.h[j] * D0.h[j];      /* v_pk_mul_f16 */               \
            A1.h[j] = S1.h[j] * D1.h[j];                                       \
            A2.u[j] = 0u;                                                      \
        }                                                                      \
        if (q == 0) {                         /* k = 64..71 -> e_geo[e][0..7]*/\
            A2.h[0] = cvt2h(G0[0], G0[1]);                                     \
            A2.h[1] = cvt2h(G0[2], G0[3]);                                     \
            A2.h[2] = cvt2h(G1[0], G1[1]);                                     \
            A2.h[3] = cvt2h(G1[2], G1[3]);                                     \
        }                                                                      \
        if (PREF)                              /* re-arm this gather set */    \
            GATHER(S0, S1, D0, D1, G0, G1, sI, dI, (tl) + 2 * nwaves);         \
        /* swapped operands: C^T -> lane(q,mm): edge=mm, n=t*16+q*4+i */       \
        f32x4 acc[4];                                                          \
        _Pragma("unroll")                                                      \
        for (int t = 0; t < 4; ++t) {                                          \
            f32x4 c = {0.f, 0.f, 0.f, 0.f};                                    \
            c = __builtin_amdgcn_mfma_f32_16x16x32_f16(bfr[0][t], A0.f, c, 0, 0, 0); \
            c = __builtin_amdgcn_mfma_f32_16x16x32_f16(bfr[1][t], A1.f, c, 0, 0, 0); \
            c = __builtin_amdgcn_mfma_f32_16x16x32_f16(bfr[2][t], A2.f, c, 0, 0, 0); \
            acc[t] = c;                                                        \
        }                                                                      \
        /* transpose via LDS: 4x b128 writes, rotate-swizzled, conflict-free */\
        _Pragma("unroll")                                                      \
        for (int t = 0; t < 4; ++t)                                            \
            *(f32x4*)&tileb[wbase + (((t + mm) & 3) << 4)] = acc[t];           \
        asm volatile("s_waitcnt lgkmcnt(0)" ::: "memory"); /* wave-sync */     \
        _Pragma("unroll")                                                      \
        for (int c2 = 0; c2 < 4; ++c2) {                                       \
            int b = BQ[c2];                                                    \
            f32x4 v = *(const f32x4*)&tileb[rbase + c2 * 256];                 \
            u32x4 gb = *(const u32x4*)&GBl[b * 64 + ((mm ^ (b & 15)) << 2)];   \
            f32x4 r;                                                           \
            _Pragma("unroll")                                                  \
            for (int i = 0; i < 4; ++i) {                                      \
                union { unsigned u; _Float16 h[2]; } cv;                       \
                cv.u = gb[i];                                                  \
                float x = fmaf(v[i], (float)cv.h[0], (float)cv.h[1]);          \
                r[i] = x > 0.f ? x : 0.f;                                      \
            }                                                                  \
            __builtin_nontemporal_store(r,                                     \
                (f32x4*)(out + (size_t)e0 * 64 + c2 * 256 + lane * 4));        \
        }                                                                      \
        if (PREF) {                                                            \
            _Pragma("unroll")                                                  \
            for (int c2 = 0; c2 < 4; ++c2) BQ[c2] = bqI[c2];                   \
        }                                                                      \
    }

    // 4 tiles, 2-deep pipeline: bodies A/B alternate gather sets
    BODY(sA0, sA1, dA0, dA1, gA0, gA1, bqA, t0,              true,  siA, diA, bqiA);
    BODY(sB0, sB1, dB0, dB1, gB0, gB1, bqB, t0 + nwaves,     true,  siB, diB, bqiB);
    BODY(sA0, sA1, dA0, dA1, gA0, gA1, bqA, t0 + 2 * nwaves, false, siA, diA, bqiA);
    BODY(sB0, sB1, dB0, dB1, gB0, gB1, bqB, t0 + 3 * nwaves, false, siB, diB, bqiB);

#undef BODY
#undef GATHER
#undef LOAD_IDX
}

extern "C" void kernel_launch(void* const* d_in, const int* in_sizes, int n_in,
                              void* d_out, int out_size, void* d_ws, size_t ws_size,
                              hipStream_t stream) {
    const float* node_feats = (const float*)d_in[0];
    const int*   edge_index = (const int*)  d_in[1];
    const float* e_geo      = (const float*)d_in[2];
    const float* cond       = (const float*)d_in[3];
    const int*   ebatch     = (const int*)  d_in[4];
    const float* Wn         = (const float*)d_in[5];
    const float* bn         = (const float*)d_in[6];
    const float* Wg         = (const float*)d_in[7];
    const float* bg         = (const float*)d_in[8];
    const float* Wc         = (const float*)d_in[9];
    const float* bc         = (const float*)d_in[10];
    const float* Wx         = (const float*)d_in[11];
    float* out = (float*)d_out;

    char* ws = (char*)d_ws;
    unsigned*       gbpack = (unsigned*)(ws);                 // 16384 B
    unsigned short* Bfrag  = (unsigned short*)(ws + 16384);   // 12288 B
    unsigned short* nprojh = (unsigned short*)(ws + 32768);   // 12.8 MB

    hipLaunchKernelGGL(pre_kernel, dim3(PREP_BLOCKS + NPROJ_BLOCKS), dim3(256), 0, stream,
                       cond, Wc, bc, Wg, bg, Wx, node_feats, Wn, bn,
                       gbpack, Bfrag, nprojh);
    hipLaunchKernelGGL(edge_kernel, dim3(EDGE_BLOCKS), dim3(256), 0, stream,
                       nprojh, edge_index, e_geo, ebatch, Bfrag, gbpack, out);
}

// Round 7
// 334.993 us; speedup vs baseline: 1.1951x; 1.1951x over previous
//
#include <hip/hip_runtime.h>

#define N_NODES   100000
#define N_EDGES   800000
#define NODE_DIM  64
#define EDGE_DIM  64
#define GEO_DIM   8
#define GEO_OUT   32
#define COND_DIM  512
#define N_GRAPHS  64

#define PREP_BLOCKS   65
#define NPROJ_BLOCKS  3125
#define EDGE_BLOCKS   3125   // 12500 waves x 4 tiles = 50000 = N_EDGES/16 exactly

typedef float          f32x4 __attribute__((ext_vector_type(4)));
typedef unsigned       u32x4 __attribute__((ext_vector_type(4)));
typedef unsigned short u16x8 __attribute__((ext_vector_type(8)));
typedef _Float16       f16x8 __attribute__((ext_vector_type(8)));
typedef _Float16       f16x2 __attribute__((ext_vector_type(2)));

__device__ __forceinline__ unsigned short f2h(float f) {   // f32 -> fp16 RNE
    _Float16 h = (_Float16)f;
    union { _Float16 h; unsigned short u; } cv;
    cv.h = h;
    return cv.u;
}
__device__ __forceinline__ f16x2 cvt2h(float lo, float hi) {
    f16x2 r;
    r[0] = (_Float16)lo;
    r[1] = (_Float16)hi;
    return r;
}

// ---------------------------------------------------------------------------
// pre: fused prep + nproj.
//   blocks 0..63   : FiLM gamma/beta2 per graph -> gbpack (fp16 pair per
//                    feature), XOR-swizzled: dword addr for (g, j) is
//                    g*64 + (((j>>2) ^ (g&15))<<2) + (j&3)
//   block  64      : Bfrag (fp16, 6144) in MFMA-fragment order:
//                    idx = ((c*4+t)*64 + lane)*8 + j holds
//                    B[k=c*32+(lane>>4)*8+j][n=t*16+(lane&15)] of folded 96x64:
//                    rows 0..63 = Wx[0:64]; 64..71 = Wg@Wx[64:96]; 72..95 = 0
//   blocks 65..    : nproj  n_projh[n][j] = fp16(node_feats[n] @ Wn[:,j] + bn[j])
//                    2 nodes in flight per wave (scalar-load latency overlap)
// ---------------------------------------------------------------------------
__global__ __launch_bounds__(256) void pre_kernel(
        const float* __restrict__ cond, const float* __restrict__ Wc,
        const float* __restrict__ bc,   const float* __restrict__ Wg,
        const float* __restrict__ bg,   const float* __restrict__ Wx,
        const float* __restrict__ nf,   const float* __restrict__ Wn,
        const float* __restrict__ bn,
        unsigned* __restrict__ gbpack, unsigned short* __restrict__ Bfrag,
        unsigned short* __restrict__ nprojh) {
    int t = threadIdx.x;
    int g = blockIdx.x;
    if (g < N_GRAPHS) {
        __shared__ float condl[COND_DIM];
        __shared__ float gbl[128];
        for (int i = t; i < COND_DIM; i += 256) condl[i] = cond[g * COND_DIM + i];
        __syncthreads();
        if (t < 128) {
            float acc = bc[t];
            #pragma unroll 8
            for (int k = 0; k < COND_DIM; ++k) acc += condl[k] * Wc[k * 128 + t];
            gbl[t] = acc;
        }
        __syncthreads();
        if (t < 64) {
            float gam = gbl[t] + 1.0f;
            float bet = gbl[64 + t];
            float cv = 0.0f;
            #pragma unroll
            for (int i = 0; i < GEO_OUT; ++i) cv += bg[i] * Wx[(64 + i) * 64 + t];
            union { unsigned u; _Float16 h[2]; } pk;
            pk.h[0] = (_Float16)gam;
            pk.h[1] = (_Float16)(bet + cv * gam);
            gbpack[g * 64 + (((t >> 2) ^ (g & 15)) << 2) + (t & 3)] = pk.u;
        }
    } else if (g == N_GRAPHS) {
        for (int idx = t; idx < 6144; idx += 256) {
            int j    = idx & 7;
            int lane = (idx >> 3) & 63;
            int ct   = idx >> 9;
            int c    = ct >> 2, tt = ct & 3;
            int k = c * 32 + ((lane >> 4) & 3) * 8 + j;
            int n = tt * 16 + (lane & 15);
            float val;
            if (k < 64) {
                val = Wx[k * 64 + n];
            } else if (k < 72) {
                float s = 0.f;
                #pragma unroll
                for (int i = 0; i < GEO_OUT; ++i)
                    s += Wg[(k - 64) * GEO_OUT + i] * Wx[(64 + i) * 64 + n];
                val = s;
            } else {
                val = 0.f;
            }
            Bfrag[idx] = f2h(val);
        }
    } else {
        int lane = t & 63;
        int wid    = ((g - PREP_BLOCKS) * 256 + t) >> 6;
        const int nwaves = (NPROJ_BLOCKS * 256) >> 6;   // 12500
        float wcol[64];
        #pragma unroll
        for (int k = 0; k < 64; ++k) wcol[k] = Wn[k * 64 + lane];
        float bnl = bn[lane];
        // N_NODES = 12500 waves * 8 nodes exactly; 8 is even -> unroll-2 safe
        for (int node = wid; node < N_NODES; node += 2 * nwaves) {
            int nu0 = __builtin_amdgcn_readfirstlane(node);
            int nu1 = __builtin_amdgcn_readfirstlane(node + nwaves);
            const float* row0 = nf + (size_t)nu0 * 64;
            const float* row1 = nf + (size_t)nu1 * 64;
            float a0 = 0.f, a1 = 0.f, a2 = 0.f, a3 = bnl;
            float c0 = 0.f, c1 = 0.f, c2 = 0.f, c3 = bnl;
            #pragma unroll
            for (int k = 0; k < 64; k += 4) {
                a0 = fmaf(row0[k    ], wcol[k    ], a0);
                a1 = fmaf(row0[k + 1], wcol[k + 1], a1);
                a2 = fmaf(row0[k + 2], wcol[k + 2], a2);
                a3 = fmaf(row0[k + 3], wcol[k + 3], a3);
                c0 = fmaf(row1[k    ], wcol[k    ], c0);
                c1 = fmaf(row1[k + 1], wcol[k + 1], c1);
                c2 = fmaf(row1[k + 2], wcol[k + 2], c2);
                c3 = fmaf(row1[k + 3], wcol[k + 3], c3);
            }
            nprojh[(size_t)nu0 * 64 + lane] = f2h((a0 + a1) + (a2 + a3));
            nprojh[(size_t)nu1 * 64 + lane] = f2h((c0 + c1) + (c2 + c3));
        }
    }
}

// ---------------------------------------------------------------------------
// edge: per wave EXACTLY 4 tiles of 16 edges (grid must be EDGE_BLOCKS).
//   R5-proven structure (332 us): SWAPPED-OPERAND fp16 MFMA; B fragments in
//   LDS (register-B variant R6 spilled to scratch: +89MB det. writes, 153us).
//   Packed fp16 gamma/beta in LDS -> epilogue has zero global loads, the
//   depth-2 gather prefetch is never vmcnt-drained.  Transpose via
//   rotate-swizzled LDS tile, contiguous 1KB nt wave stores.
// ---------------------------------------------------------------------------
__global__ __launch_bounds__(256, 4) void edge_kernel(
        const unsigned short* __restrict__ nprojh,
        const int*   __restrict__ eidx,
        const float* __restrict__ egeo,
        const int*   __restrict__ ebatch,
        const unsigned short* __restrict__ Bfrag,
        const unsigned* __restrict__ gbpack,
        float* __restrict__ out) {
    int lane = threadIdx.x & 63;
    int q  = lane >> 4;
    int mm = lane & 15;
    int wv = threadIdx.x >> 6;

    __shared__ unsigned short Bl[6144];     // 12.3KB B fragments (fp16)
    __shared__ unsigned GBl[4096];          // 16KB packed gamma/beta (swizzled)
    __shared__ float ldsT[4][16 * 64];      // 4KB per-wave transpose tile
    float* tileb = ldsT[wv];

    for (int i = threadIdx.x; i < 768; i += 256)
        ((f32x4*)Bl)[i] = ((const f32x4*)Bfrag)[i];
    for (int i = threadIdx.x; i < 4096; i += 256)
        GBl[i] = gbpack[i];                 // already swizzled in global
    __syncthreads();

    // Rotate-swizzled transpose addresses (lane-only):
    // write (per t): float addr = mm*64 + ((t+mm)&3)*16 + q*4   (b128)
    // read  (per c): float addr = rbase + c*256                 (b128)
    const int wbase = mm * 64 + q * 4;
    const int rbase = (lane >> 4) * 64 +
                      (((((lane >> 2) & 3) + (lane >> 4)) & 3) << 4) +
                      (lane & 3) * 4;

    int wid = (blockIdx.x * blockDim.x + threadIdx.x) >> 6;
    const int nwaves = (EDGE_BLOCKS * 256) >> 6;        // 12500
    const int t0 = wid;                                  // tiles t0 + k*nwaves

    union HU { u16x8 v; f16x2 h[4]; unsigned u[4]; f16x8 f; };

    // persistent pipeline state: 2 gather sets + 2 pending index sets
    HU   sA0, sA1, dA0, dA1;  f32x4 gA0 = {0,0,0,0}, gA1 = {0,0,0,0};
    HU   sB0, sB1, dB0, dB1;  f32x4 gB0 = {0,0,0,0}, gB1 = {0,0,0,0};
    int  bqA[4], bqB[4];      // batch ids for epilogue rows of current tiles
    int  siA, diA, bqiA[4];   // indices for tile t0+2*nw (body A's prefetch)
    int  siB, diB, bqiB[4];   // indices for tile t0+3*nw (body B's prefetch)

#define LOAD_IDX(sI, dI, bqI, tl)                                              \
    {                                                                          \
        int e0n = (tl) * 16;                                                   \
        sI = __builtin_nontemporal_load(eidx + e0n + mm);                      \
        dI = __builtin_nontemporal_load(eidx + N_EDGES + e0n + mm);            \
        _Pragma("unroll")                                                      \
        for (int c = 0; c < 4; ++c)                                            \
            bqI[c] = __builtin_nontemporal_load(ebatch + e0n + c * 4 + q);     \
    }

#define GATHER(S0, S1, D0, D1, G0, G1, sI, dI, tl)                             \
    {                                                                          \
        const u16x8* ps = (const u16x8*)(nprojh + (size_t)(sI) * 64 + q * 8);  \
        const u16x8* pd = (const u16x8*)(nprojh + (size_t)(dI) * 64 + q * 8);  \
        S0.v = ps[0]; S1.v = ps[4];                                            \
        D0.v = pd[0]; D1.v = pd[4];                                            \
        if (q == 0) {                                                          \
            int e0n = (tl) * 16;                                               \
            G0 = __builtin_nontemporal_load((const f32x4*)(egeo + (size_t)(e0n + mm) * 8));     \
            G1 = __builtin_nontemporal_load((const f32x4*)(egeo + (size_t)(e0n + mm) * 8 + 4)); \
        }                                                                      \
    }

    // prologue: ALL index loads issue first (one latency, not two serial),
    // then the two gather sets for tiles t0, t0+nw.
    {
        int si0, di0, si1, di1;
        LOAD_IDX(si0, di0, bqA, t0);
        LOAD_IDX(si1, di1, bqB, t0 + nwaves);
        LOAD_IDX(siA, diA, bqiA, t0 + 2 * nwaves);
        LOAD_IDX(siB, diB, bqiB, t0 + 3 * nwaves);
        GATHER(sA0, sA1, dA0, dA1, gA0, gA1, si0, di0, t0);
        GATHER(sB0, sB1, dB0, dB1, gB0, gB1, si1, di1, t0 + nwaves);
    }

#define BODY(S0, S1, D0, D1, G0, G1, BQ, tl, PREF, sI, dI, bqI)                \
    {                                                                          \
        int e0 = (tl) * 16;                                                    \
        HU A0, A1, A2;                                                         \
        _Pragma("unroll")                                                      \
        for (int j = 0; j < 4; ++j) {                                          \
            A0.h[j] = S0.h[j] * D0.h[j];      /* v_pk_mul_f16 */               \
            A1.h[j] = S1.h[j] * D1.h[j];                                       \
            A2.u[j] = 0u;                                                      \
        }                                                                      \
        if (q == 0) {                         /* k = 64..71 -> e_geo[e][0..7]*/\
            A2.h[0] = cvt2h(G0[0], G0[1]);                                     \
            A2.h[1] = cvt2h(G0[2], G0[3]);                                     \
            A2.h[2] = cvt2h(G1[0], G1[1]);                                     \
            A2.h[3] = cvt2h(G1[2], G1[3]);                                     \
        }                                                                      \
        if (PREF)                              /* re-arm this gather set */    \
            GATHER(S0, S1, D0, D1, G0, G1, sI, dI, (tl) + 2 * nwaves);         \
        /* swapped operands: C^T -> lane(q,mm): edge=mm, n=t*16+q*4+i */       \
        f32x4 acc[4];                                                          \
        _Pragma("unroll")                                                      \
        for (int t = 0; t < 4; ++t) {                                          \
            f32x4 c = {0.f, 0.f, 0.f, 0.f};                                    \
            c = __builtin_amdgcn_mfma_f32_16x16x32_f16(                        \
                    *(const f16x8*)(Bl + ((0 * 4 + t) * 64 + lane) * 8), A0.f, c, 0, 0, 0); \
            c = __builtin_amdgcn_mfma_f32_16x16x32_f16(                        \
                    *(const f16x8*)(Bl + ((1 * 4 + t) * 64 + lane) * 8), A1.f, c, 0, 0, 0); \
            c = __builtin_amdgcn_mfma_f32_16x16x32_f16(                        \
                    *(const f16x8*)(Bl + ((2 * 4 + t) * 64 + lane) * 8), A2.f, c, 0, 0, 0); \
            acc[t] = c;                                                        \
        }                                                                      \
        /* transpose via LDS: 4x b128 writes, rotate-swizzled, conflict-free */\
        _Pragma("unroll")                                                      \
        for (int t = 0; t < 4; ++t)                                            \
            *(f32x4*)&tileb[wbase + (((t + mm) & 3) << 4)] = acc[t];           \
        asm volatile("s_waitcnt lgkmcnt(0)" ::: "memory"); /* wave-sync */     \
        _Pragma("unroll")                                                      \
        for (int c2 = 0; c2 < 4; ++c2) {                                       \
            int b = BQ[c2];                                                    \
            f32x4 v = *(const f32x4*)&tileb[rbase + c2 * 256];                 \
            u32x4 gb = *(const u32x4*)&GBl[b * 64 + ((mm ^ (b & 15)) << 2)];   \
            f32x4 r;                                                           \
            _Pragma("unroll")                                                  \
            for (int i = 0; i < 4; ++i) {                                      \
                union { unsigned u; _Float16 h[2]; } cv;                       \
                cv.u = gb[i];                                                  \
                float x = fmaf(v[i], (float)cv.h[0], (float)cv.h[1]);          \
                r[i] = x > 0.f ? x : 0.f;                                      \
            }                                                                  \
            __builtin_nontemporal_store(r,                                     \
                (f32x4*)(out + (size_t)e0 * 64 + c2 * 256 + lane * 4));        \
        }                                                                      \
        if (PREF) {                                                            \
            _Pragma("unroll")                                                  \
            for (int c2 = 0; c2 < 4; ++c2) BQ[c2] = bqI[c2];                   \
        }                                                                      \
    }

    // 4 tiles, 2-deep pipeline: bodies A/B alternate gather sets
    BODY(sA0, sA1, dA0, dA1, gA0, gA1, bqA, t0,              true,  siA, diA, bqiA);
    BODY(sB0, sB1, dB0, dB1, gB0, gB1, bqB, t0 + nwaves,     true,  siB, diB, bqiB);
    BODY(sA0, sA1, dA0, dA1, gA0, gA1, bqA, t0 + 2 * nwaves, false, siA, diA, bqiA);
    BODY(sB0, sB1, dB0, dB1, gB0, gB1, bqB, t0 + 3 * nwaves, false, siB, diB, bqiB);

#undef BODY
#undef GATHER
#undef LOAD_IDX
}

extern "C" void kernel_launch(void* const* d_in, const int* in_sizes, int n_in,
                              void* d_out, int out_size, void* d_ws, size_t ws_size,
                              hipStream_t stream) {
    const float* node_feats = (const float*)d_in[0];
    const int*   edge_index = (const int*)  d_in[1];
    const float* e_geo      = (const float*)d_in[2];
    const float* cond       = (const float*)d_in[3];
    const int*   ebatch     = (const int*)  d_in[4];
    const float* Wn         = (const float*)d_in[5];
    const float* bn         = (const float*)d_in[6];
    const float* Wg         = (const float*)d_in[7];
    const float* bg         = (const float*)d_in[8];
    const float* Wc         = (const float*)d_in[9];
    const float* bc         = (const float*)d_in[10];
    const float* Wx         = (const float*)d_in[11];
    float* out = (float*)d_out;

    char* ws = (char*)d_ws;
    unsigned*       gbpack = (unsigned*)(ws);                 // 16384 B
    unsigned short* Bfrag  = (unsigned short*)(ws + 16384);   // 12288 B
    unsigned short* nprojh = (unsigned short*)(ws + 32768);   // 12.8 MB

    hipLaunchKernelGGL(pre_kernel, dim3(PREP_BLOCKS + NPROJ_BLOCKS), dim3(256), 0, stream,
                       cond, Wc, bc, Wg, bg, Wx, node_feats, Wn, bn,
                       gbpack, Bfrag, nprojh);
    hipLaunchKernelGGL(edge_kernel, dim3(EDGE_BLOCKS), dim3(256), 0, stream,
                       nprojh, edge_index, e_geo, ebatch, Bfrag, gbpack, out);
}

// Round 8
// 329.481 us; speedup vs baseline: 1.2151x; 1.0167x over previous
//
#include <hip/hip_runtime.h>

#define N_NODES   100000
#define N_EDGES   800000
#define NODE_DIM  64
#define EDGE_DIM  64
#define GEO_DIM   8
#define GEO_OUT   32
#define COND_DIM  512
#define N_GRAPHS  64

#define PREP_BLOCKS   65
#define NPROJ_BLOCKS  3125
#define EDGE_BLOCKS   1250   // 5000 waves x 10 tiles = 50000 = N_EDGES/16 exactly

typedef float          f32x4 __attribute__((ext_vector_type(4)));
typedef unsigned       u32x4 __attribute__((ext_vector_type(4)));
typedef unsigned short u16x8 __attribute__((ext_vector_type(8)));
typedef _Float16       f16x8 __attribute__((ext_vector_type(8)));
typedef _Float16       f16x2 __attribute__((ext_vector_type(2)));

__device__ __forceinline__ unsigned short f2h(float f) {   // f32 -> fp16 RNE
    _Float16 h = (_Float16)f;
    union { _Float16 h; unsigned short u; } cv;
    cv.h = h;
    return cv.u;
}
__device__ __forceinline__ f16x2 cvt2h(float lo, float hi) {
    f16x2 r;
    r[0] = (_Float16)lo;
    r[1] = (_Float16)hi;
    return r;
}

// ---------------------------------------------------------------------------
// pre: fused prep + nproj (unchanged from R7).
//   blocks 0..63   : FiLM gamma/beta2 -> gbpack (fp16 pair, XOR-swizzled)
//   block  64      : Bfrag (fp16, 6144) in MFMA-fragment order (folded 96x64)
//   blocks 65..    : nproj  n_projh[n][j] = fp16(node_feats[n] @ Wn[:,j] + bn[j])
// ---------------------------------------------------------------------------
__global__ __launch_bounds__(256) void pre_kernel(
        const float* __restrict__ cond, const float* __restrict__ Wc,
        const float* __restrict__ bc,   const float* __restrict__ Wg,
        const float* __restrict__ bg,   const float* __restrict__ Wx,
        const float* __restrict__ nf,   const float* __restrict__ Wn,
        const float* __restrict__ bn,
        unsigned* __restrict__ gbpack, unsigned short* __restrict__ Bfrag,
        unsigned short* __restrict__ nprojh) {
    int t = threadIdx.x;
    int g = blockIdx.x;
    if (g < N_GRAPHS) {
        __shared__ float condl[COND_DIM];
        __shared__ float gbl[128];
        for (int i = t; i < COND_DIM; i += 256) condl[i] = cond[g * COND_DIM + i];
        __syncthreads();
        if (t < 128) {
            float acc = bc[t];
            #pragma unroll 8
            for (int k = 0; k < COND_DIM; ++k) acc += condl[k] * Wc[k * 128 + t];
            gbl[t] = acc;
        }
        __syncthreads();
        if (t < 64) {
            float gam = gbl[t] + 1.0f;
            float bet = gbl[64 + t];
            float cv = 0.0f;
            #pragma unroll
            for (int i = 0; i < GEO_OUT; ++i) cv += bg[i] * Wx[(64 + i) * 64 + t];
            union { unsigned u; _Float16 h[2]; } pk;
            pk.h[0] = (_Float16)gam;
            pk.h[1] = (_Float16)(bet + cv * gam);
            gbpack[g * 64 + (((t >> 2) ^ (g & 15)) << 2) + (t & 3)] = pk.u;
        }
    } else if (g == N_GRAPHS) {
        for (int idx = t; idx < 6144; idx += 256) {
            int j    = idx & 7;
            int lane = (idx >> 3) & 63;
            int ct   = idx >> 9;
            int c    = ct >> 2, tt = ct & 3;
            int k = c * 32 + ((lane >> 4) & 3) * 8 + j;
            int n = tt * 16 + (lane & 15);
            float val;
            if (k < 64) {
                val = Wx[k * 64 + n];
            } else if (k < 72) {
                float s = 0.f;
                #pragma unroll
                for (int i = 0; i < GEO_OUT; ++i)
                    s += Wg[(k - 64) * GEO_OUT + i] * Wx[(64 + i) * 64 + n];
                val = s;
            } else {
                val = 0.f;
            }
            Bfrag[idx] = f2h(val);
        }
    } else {
        int lane = t & 63;
        int wid    = ((g - PREP_BLOCKS) * 256 + t) >> 6;
        const int nwaves = (NPROJ_BLOCKS * 256) >> 6;   // 12500
        float wcol[64];
        #pragma unroll
        for (int k = 0; k < 64; ++k) wcol[k] = Wn[k * 64 + lane];
        float bnl = bn[lane];
        // N_NODES = 12500 waves * 8 nodes exactly; 8 is even -> unroll-2 safe
        for (int node = wid; node < N_NODES; node += 2 * nwaves) {
            int nu0 = __builtin_amdgcn_readfirstlane(node);
            int nu1 = __builtin_amdgcn_readfirstlane(node + nwaves);
            const float* row0 = nf + (size_t)nu0 * 64;
            const float* row1 = nf + (size_t)nu1 * 64;
            float a0 = 0.f, a1 = 0.f, a2 = 0.f, a3 = bnl;
            float c0 = 0.f, c1 = 0.f, c2 = 0.f, c3 = bnl;
            #pragma unroll
            for (int k = 0; k < 64; k += 4) {
                a0 = fmaf(row0[k    ], wcol[k    ], a0);
                a1 = fmaf(row0[k + 1], wcol[k + 1], a1);
                a2 = fmaf(row0[k + 2], wcol[k + 2], a2);
                a3 = fmaf(row0[k + 3], wcol[k + 3], a3);
                c0 = fmaf(row1[k    ], wcol[k    ], c0);
                c1 = fmaf(row1[k + 1], wcol[k + 1], c1);
                c2 = fmaf(row1[k + 2], wcol[k + 2], c2);
                c3 = fmaf(row1[k + 3], wcol[k + 3], c3);
            }
            nprojh[(size_t)nu0 * 64 + lane] = f2h((a0 + a1) + (a2 + a3));
            nprojh[(size_t)nu1 * 64 + lane] = f2h((c0 + c1) + (c2 + c3));
        }
    }
}

// ---------------------------------------------------------------------------
// edge: per wave EXACTLY 10 tiles of 16 edges (grid must be EDGE_BLOCKS=1250;
//   5000 waves x 10 tiles = 50000).  R5-proven steady-state structure:
//   SWAPPED-OPERAND fp16 MFMA; B fragments + packed fp16 gamma/beta in LDS;
//   rotate-swizzled LDS transpose; contiguous 1KB nt wave stores; zero global
//   loads in the epilogue (no vmcnt drain of the gather prefetch).
//   New: rolling 2-deep pipeline across 10 bodies -- body k consumes gather
//   T(k-1), re-arms gather T(k+1) (2-body distance), reloads idx T(k+3).
//   8/10 bodies fully pipelined (was 2/4); ~4.9 blocks/CU = one resident
//   generation; Bl/GBl staging traffic 2.5x lower (1250 vs 3125 blocks).
// ---------------------------------------------------------------------------
__global__ __launch_bounds__(256, 4) void edge_kernel(
        const unsigned short* __restrict__ nprojh,
        const int*   __restrict__ eidx,
        const float* __restrict__ egeo,
        const int*   __restrict__ ebatch,
        const unsigned short* __restrict__ Bfrag,
        const unsigned* __restrict__ gbpack,
        float* __restrict__ out) {
    int lane = threadIdx.x & 63;
    int q  = lane >> 4;
    int mm = lane & 15;
    int wv = threadIdx.x >> 6;

    __shared__ unsigned short Bl[6144];     // 12.3KB B fragments (fp16)
    __shared__ unsigned GBl[4096];          // 16KB packed gamma/beta (swizzled)
    __shared__ float ldsT[4][16 * 64];      // 4KB per-wave transpose tile
    float* tileb = ldsT[wv];

    for (int i = threadIdx.x; i < 768; i += 256)
        ((f32x4*)Bl)[i] = ((const f32x4*)Bfrag)[i];
    for (int i = threadIdx.x; i < 4096; i += 256)
        GBl[i] = gbpack[i];                 // already swizzled in global
    __syncthreads();

    // Rotate-swizzled transpose addresses (lane-only):
    // write (per t): float addr = mm*64 + ((t+mm)&3)*16 + q*4   (b128)
    // read  (per c): float addr = rbase + c*256                 (b128)
    const int wbase = mm * 64 + q * 4;
    const int rbase = (lane >> 4) * 64 +
                      (((((lane >> 2) & 3) + (lane >> 4)) & 3) << 4) +
                      (lane & 3) * 4;

    int wid = (blockIdx.x * blockDim.x + threadIdx.x) >> 6;
    const int nwaves = (EDGE_BLOCKS * 256) >> 6;        // 5000
    const int t0 = wid;                                  // tiles t0 + k*nwaves

    union HU { u16x8 v; f16x2 h[4]; unsigned u[4]; f16x8 f; };

    // persistent pipeline state: 2 gather sets, each with cur/next batch ids
    HU   sA0, sA1, dA0, dA1;  f32x4 gA0 = {0,0,0,0}, gA1 = {0,0,0,0};
    HU   sB0, sB1, dB0, dB1;  f32x4 gB0 = {0,0,0,0}, gB1 = {0,0,0,0};
    int  bqAc[4], bqAn[4], bqBc[4], bqBn[4];
    int  siA, diA;            // indices feeding set A's next gather
    int  siB, diB;            // indices feeding set B's next gather

#define LOAD_IDX(sI, dI, bqI, tl)                                              \
    {                                                                          \
        int e0n = (tl) * 16;                                                   \
        sI = __builtin_nontemporal_load(eidx + e0n + mm);                      \
        dI = __builtin_nontemporal_load(eidx + N_EDGES + e0n + mm);            \
        _Pragma("unroll")                                                      \
        for (int c = 0; c < 4; ++c)                                            \
            bqI[c] = __builtin_nontemporal_load(ebatch + e0n + c * 4 + q);     \
    }

#define GATHER(S0, S1, D0, D1, G0, G1, sI, dI, tl)                             \
    {                                                                          \
        const u16x8* ps = (const u16x8*)(nprojh + (size_t)(sI) * 64 + q * 8);  \
        const u16x8* pd = (const u16x8*)(nprojh + (size_t)(dI) * 64 + q * 8);  \
        S0.v = ps[0]; S1.v = ps[4];                                            \
        D0.v = pd[0]; D1.v = pd[4];                                            \
        if (q == 0) {                                                          \
            int e0n = (tl) * 16;                                               \
            G0 = __builtin_nontemporal_load((const f32x4*)(egeo + (size_t)(e0n + mm) * 8));     \
            G1 = __builtin_nontemporal_load((const f32x4*)(egeo + (size_t)(e0n + mm) * 8 + 4)); \
        }                                                                      \
    }

    // prologue: idx T0,T1 -> gather T0,T1 -> idx T2,T3
    {
        LOAD_IDX(siA, diA, bqAc, t0);
        LOAD_IDX(siB, diB, bqBc, t0 + nwaves);
        GATHER(sA0, sA1, dA0, dA1, gA0, gA1, siA, diA, t0);
        GATHER(sB0, sB1, dB0, dB1, gB0, gB1, siB, diB, t0 + nwaves);
        LOAD_IDX(siA, diA, bqAn, t0 + 2 * nwaves);
        LOAD_IDX(siB, diB, bqBn, t0 + 3 * nwaves);
    }

    // BODY: consume gathers for tile tl; GEN: re-arm gather for tl+2nw
    // (indices already resident in sI/dI/bqN); IEN: reload sI/dI/bqN with
    // indices for tl+4nw (consumed 2 bodies later).
#define BODY(S0, S1, D0, D1, G0, G1, BQC, BQN, tl, GEN, IEN, sI, dI)           \
    {                                                                          \
        int e0 = (tl) * 16;                                                    \
        HU A0, A1, A2;                                                         \
        _Pragma("unroll")                                                      \
        for (int j = 0; j < 4; ++j) {                                          \
            A0.h[j] = S0.h[j] * D0.h[j];      /* v_pk_mul_f16 */               \
            A1.h[j] = S1.h[j] * D1.h[j];                                       \
            A2.u[j] = 0u;                                                      \
        }                                                                      \
        if (q == 0) {                         /* k = 64..71 -> e_geo[e][0..7]*/\
            A2.h[0] = cvt2h(G0[0], G0[1]);                                     \
            A2.h[1] = cvt2h(G0[2], G0[3]);                                     \
            A2.h[2] = cvt2h(G1[0], G1[1]);                                     \
            A2.h[3] = cvt2h(G1[2], G1[3]);                                     \
        }                                                                      \
        if (GEN)                               /* re-arm this gather set */    \
            GATHER(S0, S1, D0, D1, G0, G1, sI, dI, (tl) + 2 * nwaves);         \
        /* swapped operands: C^T -> lane(q,mm): edge=mm, n=t*16+q*4+i */       \
        f32x4 acc[4];                                                          \
        _Pragma("unroll")                                                      \
        for (int t = 0; t < 4; ++t) {                                          \
            f32x4 c = {0.f, 0.f, 0.f, 0.f};                                    \
            c = __builtin_amdgcn_mfma_f32_16x16x32_f16(                        \
                    *(const f16x8*)(Bl + ((0 * 4 + t) * 64 + lane) * 8), A0.f, c, 0, 0, 0); \
            c = __builtin_amdgcn_mfma_f32_16x16x32_f16(                        \
                    *(const f16x8*)(Bl + ((1 * 4 + t) * 64 + lane) * 8), A1.f, c, 0, 0, 0); \
            c = __builtin_amdgcn_mfma_f32_16x16x32_f16(                        \
                    *(const f16x8*)(Bl + ((2 * 4 + t) * 64 + lane) * 8), A2.f, c, 0, 0, 0); \
            acc[t] = c;                                                        \
        }                                                                      \
        /* transpose via LDS: 4x b128 writes, rotate-swizzled, conflict-free */\
        _Pragma("unroll")                                                      \
        for (int t = 0; t < 4; ++t)                                            \
            *(f32x4*)&tileb[wbase + (((t + mm) & 3) << 4)] = acc[t];           \
        asm volatile("s_waitcnt lgkmcnt(0)" ::: "memory"); /* wave-sync */     \
        _Pragma("unroll")                                                      \
        for (int c2 = 0; c2 < 4; ++c2) {                                       \
            int b = BQC[c2];                                                   \
            f32x4 v = *(const f32x4*)&tileb[rbase + c2 * 256];                 \
            u32x4 gb = *(const u32x4*)&GBl[b * 64 + ((mm ^ (b & 15)) << 2)];   \
            f32x4 r;                                                           \
            _Pragma("unroll")                                                  \
            for (int i = 0; i < 4; ++i) {                                      \
                union { unsigned u; _Float16 h[2]; } cv;                       \
                cv.u = gb[i];                                                  \
                float x = fmaf(v[i], (float)cv.h[0], (float)cv.h[1]);          \
                r[i] = x > 0.f ? x : 0.f;                                      \
            }                                                                  \
            __builtin_nontemporal_store(r,                                     \
                (f32x4*)(out + (size_t)e0 * 64 + c2 * 256 + lane * 4));        \
        }                                                                      \
        if (GEN) {                             /* rotate batch-id pipeline */  \
            _Pragma("unroll")                                                  \
            for (int c2 = 0; c2 < 4; ++c2) BQC[c2] = BQN[c2];                  \
        }                                                                      \
        if (IEN)                               /* indices for tl+4nw */        \
            LOAD_IDX(sI, dI, BQN, (tl) + 4 * nwaves);                          \
    }

    // 10 tiles, 2-deep rolling pipeline: bodies alternate gather sets A/B.
    BODY(sA0, sA1, dA0, dA1, gA0, gA1, bqAc, bqAn, t0,              true,  true,  siA, diA); // T0
    BODY(sB0, sB1, dB0, dB1, gB0, gB1, bqBc, bqBn, t0 + 1 * nwaves, true,  true,  siB, diB); // T1
    BODY(sA0, sA1, dA0, dA1, gA0, gA1, bqAc, bqAn, t0 + 2 * nwaves, true,  true,  siA, diA); // T2
    BODY(sB0, sB1, dB0, dB1, gB0, gB1, bqBc, bqBn, t0 + 3 * nwaves, true,  true,  siB, diB); // T3
    BODY(sA0, sA1, dA0, dA1, gA0, gA1, bqAc, bqAn, t0 + 4 * nwaves, true,  true,  siA, diA); // T4
    BODY(sB0, sB1, dB0, dB1, gB0, gB1, bqBc, bqBn, t0 + 5 * nwaves, true,  true,  siB, diB); // T5
    BODY(sA0, sA1, dA0, dA1, gA0, gA1, bqAc, bqAn, t0 + 6 * nwaves, true,  false, siA, diA); // T6
    BODY(sB0, sB1, dB0, dB1, gB0, gB1, bqBc, bqBn, t0 + 7 * nwaves, true,  false, siB, diB); // T7
    BODY(sA0, sA1, dA0, dA1, gA0, gA1, bqAc, bqAn, t0 + 8 * nwaves, false, false, siA, diA); // T8
    BODY(sB0, sB1, dB0, dB1, gB0, gB1, bqBc, bqBn, t0 + 9 * nwaves, false, false, siB, diB); // T9

#undef BODY
#undef GATHER
#undef LOAD_IDX
}

extern "C" void kernel_launch(void* const* d_in, const int* in_sizes, int n_in,
                              void* d_out, int out_size, void* d_ws, size_t ws_size,
                              hipStream_t stream) {
    const float* node_feats = (const float*)d_in[0];
    const int*   edge_index = (const int*)  d_in[1];
    const float* e_geo      = (const float*)d_in[2];
    const float* cond       = (const float*)d_in[3];
    const int*   ebatch     = (const int*)  d_in[4];
    const float* Wn         = (const float*)d_in[5];
    const float* bn         = (const float*)d_in[6];
    const float* Wg         = (const float*)d_in[7];
    const float* bg         = (const float*)d_in[8];
    const float* Wc         = (const float*)d_in[9];
    const float* bc         = (const float*)d_in[10];
    const float* Wx         = (const float*)d_in[11];
    float* out = (float*)d_out;

    char* ws = (char*)d_ws;
    unsigned*       gbpack = (unsigned*)(ws);                 // 16384 B
    unsigned short* Bfrag  = (unsigned short*)(ws + 16384);   // 12288 B
    unsigned short* nprojh = (unsigned short*)(ws + 32768);   // 12.8 MB

    hipLaunchKernelGGL(pre_kernel, dim3(PREP_BLOCKS + NPROJ_BLOCKS), dim3(256), 0, stream,
                       cond, Wc, bc, Wg, bg, Wx, node_feats, Wn, bn,
                       gbpack, Bfrag, nprojh);
    hipLaunchKernelGGL(edge_kernel, dim3(EDGE_BLOCKS), dim3(256), 0, stream,
                       nprojh, edge_index, e_geo, ebatch, Bfrag, gbpack, out);
}